// Round 3
// baseline (5072.054 us; speedup 1.0000x reference)
//
#include <hip/hip_runtime.h>

#define B_    64
#define C_    512
#define H_    32
#define WDIM  32
#define N_    1024   // H*W
#define M3C   1536   // 3*C

// ---------------------------------------------------------------------------
// pos[c, h*W+w] = rel_h[c,h] + rel_w[c,w]   (fp32)
// ---------------------------------------------------------------------------
__global__ __launch_bounds__(256) void pos_kernel(const float* __restrict__ rel_h,
                                                  const float* __restrict__ rel_w,
                                                  float* __restrict__ pos) {
    int idx = blockIdx.x * 256 + threadIdx.x;  // over C*N
    if (idx >= C_ * N_) return;
    int c = idx >> 10;
    int n = idx & (N_ - 1);
    int h = n >> 5;
    int w = n & (WDIM - 1);
    pos[idx] = rel_h[c * H_ + h] + rel_w[c * WDIM + w];
}

// ---------------------------------------------------------------------------
// qkv[bl,o,n] = sum_c W[o,c] * x[b0+bl,c,n]  (all fp32; bl = chunk-local batch)
// GEMM per batch: M=1536(o), K=512(c), N=1024(n). 64x64 tile, BK=16.
// ---------------------------------------------------------------------------
__global__ __launch_bounds__(256) void qkv_gemm(const float* __restrict__ Wm,
                                                const float* __restrict__ x,   // already offset to b0
                                                float* __restrict__ qkv) {
    __shared__ float As[16][64 + 1];   // As[k][m]
    __shared__ float Bs[16][64];       // Bs[k][n]
    const int bl = blockIdx.z;
    const int m0 = blockIdx.y * 64;
    const int n0 = blockIdx.x * 64;
    const float* xb   = x   + (size_t)bl * C_ * N_;
    float*       outb = qkv + (size_t)bl * M3C * N_;
    const int tx = threadIdx.x, ty = threadIdx.y;
    const int tid = ty * 16 + tx;
    float acc[4][4] = {};
    for (int k0 = 0; k0 < C_; k0 += 16) {
        #pragma unroll
        for (int t = 0; t < 4; ++t) {          // A tile: W[m0+i][k0+j] -> As[j][i]
            int e = tid + t * 256;
            int i = e >> 4, j = e & 15;
            As[j][i] = Wm[(size_t)(m0 + i) * C_ + k0 + j];
        }
        #pragma unroll
        for (int t = 0; t < 4; ++t) {          // B tile: x[k0+j][n0+i] -> Bs[j][i]
            int e = tid + t * 256;
            int j = e >> 6, i = e & 63;
            Bs[j][i] = xb[(size_t)(k0 + j) * N_ + n0 + i];
        }
        __syncthreads();
        #pragma unroll
        for (int kk = 0; kk < 16; ++kk) {
            float a[4], bb[4];
            #pragma unroll
            for (int i = 0; i < 4; ++i) a[i]  = As[kk][ty * 4 + i];
            #pragma unroll
            for (int j = 0; j < 4; ++j) bb[j] = Bs[kk][tx * 4 + j];
            #pragma unroll
            for (int i = 0; i < 4; ++i)
                #pragma unroll
                for (int j = 0; j < 4; ++j)
                    acc[i][j] += a[i] * bb[j];
        }
        __syncthreads();
    }
    #pragma unroll
    for (int i = 0; i < 4; ++i)
        #pragma unroll
        for (int j = 0; j < 4; ++j)
            outb[(size_t)(m0 + ty * 4 + i) * N_ + n0 + tx * 4 + j] = acc[i][j];
}

// ---------------------------------------------------------------------------
// S[bl,n,m] = sum_{kk<1024} A[kk,n]*B[kk,m],  A=[q;pos], B=[k;q]   (fp32)
// ---------------------------------------------------------------------------
__global__ __launch_bounds__(256) void s_gemm(const float* __restrict__ qkv,
                                              const float* __restrict__ pos,
                                              float* __restrict__ S) {
    __shared__ float As[16][64];
    __shared__ float Bs[16][64];
    const int bl = blockIdx.z;
    const int n0 = blockIdx.y * 64;   // output row tile
    const int m0 = blockIdx.x * 64;   // output col tile
    const float* qb = qkv + (size_t)bl * M3C * N_;
    const float* kb = qb + (size_t)C_ * N_;
    float*       Sb = S + (size_t)bl * N_ * N_;
    const int tx = threadIdx.x, ty = threadIdx.y;
    const int tid = ty * 16 + tx;
    float acc[4][4] = {};
    for (int k0 = 0; k0 < 2 * C_; k0 += 16) {
        const float* Asrc = (k0 < C_) ? (qb + (size_t)k0 * N_)
                                      : (pos + (size_t)(k0 - C_) * N_);
        const float* Bsrc = (k0 < C_) ? (kb + (size_t)k0 * N_)
                                      : (qb + (size_t)(k0 - C_) * N_);
        #pragma unroll
        for (int t = 0; t < 4; ++t) {
            int e = tid + t * 256;
            int j = e >> 6, i = e & 63;
            As[j][i] = Asrc[(size_t)j * N_ + n0 + i];
            Bs[j][i] = Bsrc[(size_t)j * N_ + m0 + i];
        }
        __syncthreads();
        #pragma unroll
        for (int kk = 0; kk < 16; ++kk) {
            float a[4], bb[4];
            #pragma unroll
            for (int i = 0; i < 4; ++i) a[i]  = As[kk][ty * 4 + i];
            #pragma unroll
            for (int j = 0; j < 4; ++j) bb[j] = Bs[kk][tx * 4 + j];
            #pragma unroll
            for (int i = 0; i < 4; ++i)
                #pragma unroll
                for (int j = 0; j < 4; ++j)
                    acc[i][j] += a[i] * bb[j];
        }
        __syncthreads();
    }
    #pragma unroll
    for (int i = 0; i < 4; ++i)
        #pragma unroll
        for (int j = 0; j < 4; ++j)
            Sb[(size_t)(n0 + ty * 4 + i) * N_ + m0 + tx * 4 + j] = acc[i][j];
}

// ---------------------------------------------------------------------------
// Row softmax over m (row length 1024), in place (fp32).
// ---------------------------------------------------------------------------
__device__ __forceinline__ float waveMax(float v) {
    #pragma unroll
    for (int o = 32; o > 0; o >>= 1) v = fmaxf(v, __shfl_down(v, o));
    return v;
}
__device__ __forceinline__ float waveSum(float v) {
    #pragma unroll
    for (int o = 32; o > 0; o >>= 1) v += __shfl_down(v, o);
    return v;
}

__global__ __launch_bounds__(256) void softmax_kernel(float* __restrict__ S) {
    float* Sr = S + (size_t)blockIdx.x * N_;
    const int tid = threadIdx.x;
    float4 v = reinterpret_cast<float4*>(Sr)[tid];
    __shared__ float redm[4];
    __shared__ float reds[4];
    const int wave = tid >> 6, lane = tid & 63;

    float m = fmaxf(fmaxf(v.x, v.y), fmaxf(v.z, v.w));
    m = waveMax(m);
    if (lane == 0) redm[wave] = m;
    __syncthreads();
    m = fmaxf(fmaxf(redm[0], redm[1]), fmaxf(redm[2], redm[3]));

    v.x = __expf(v.x - m); v.y = __expf(v.y - m);
    v.z = __expf(v.z - m); v.w = __expf(v.w - m);
    float s = v.x + v.y + v.z + v.w;
    s = waveSum(s);
    if (lane == 0) reds[wave] = s;
    __syncthreads();
    s = reds[0] + reds[1] + reds[2] + reds[3];
    const float inv = 1.0f / s;
    v.x *= inv; v.y *= inv; v.z *= inv; v.w *= inv;
    reinterpret_cast<float4*>(Sr)[tid] = v;
}

// ---------------------------------------------------------------------------
// out[b0+bl,c,n] = sum_m v[bl,c,m] * P[bl,n,m]   (fp32; A*B^T, contraction contiguous)
// ---------------------------------------------------------------------------
__global__ __launch_bounds__(256) void out_gemm(const float* __restrict__ qkv,
                                                const float* __restrict__ P,
                                                float* __restrict__ out) {  // already offset to b0
    __shared__ float As[16][64 + 1];   // As[m-sub][c]
    __shared__ float Bs[16][64 + 1];   // Bs[m-sub][n]
    const int bl = blockIdx.z;
    const int c0 = blockIdx.y * 64;
    const int n0 = blockIdx.x * 64;
    const float* vb   = qkv + (size_t)bl * M3C * N_ + (size_t)2 * C_ * N_;
    const float* Pb   = P   + (size_t)bl * N_ * N_;
    float*       outb = out + (size_t)bl * C_ * N_;
    const int tx = threadIdx.x, ty = threadIdx.y;
    const int tid = ty * 16 + tx;
    float acc[4][4] = {};
    for (int k0 = 0; k0 < N_; k0 += 16) {
        #pragma unroll
        for (int t = 0; t < 4; ++t) {
            int e = tid + t * 256;
            int i = e >> 4, j = e & 15;
            As[j][i] = vb[(size_t)(c0 + i) * N_ + k0 + j];
            Bs[j][i] = Pb[(size_t)(n0 + i) * N_ + k0 + j];
        }
        __syncthreads();
        #pragma unroll
        for (int kk = 0; kk < 16; ++kk) {
            float a[4], bb[4];
            #pragma unroll
            for (int i = 0; i < 4; ++i) a[i]  = As[kk][ty * 4 + i];
            #pragma unroll
            for (int j = 0; j < 4; ++j) bb[j] = Bs[kk][tx * 4 + j];
            #pragma unroll
            for (int i = 0; i < 4; ++i)
                #pragma unroll
                for (int j = 0; j < 4; ++j)
                    acc[i][j] += a[i] * bb[j];
        }
        __syncthreads();
    }
    #pragma unroll
    for (int i = 0; i < 4; ++i)
        #pragma unroll
        for (int j = 0; j < 4; ++j)
            outb[(size_t)(c0 + ty * 4 + i) * N_ + n0 + tx * 4 + j] = acc[i][j];
}

// ---------------------------------------------------------------------------
extern "C" void kernel_launch(void* const* d_in, const int* in_sizes, int n_in,
                              void* d_out, int out_size, void* d_ws, size_t ws_size,
                              hipStream_t stream) {
    const float* x     = (const float*)d_in[0];
    const float* Wm    = (const float*)d_in[1];
    const float* rel_h = (const float*)d_in[2];
    const float* rel_w = (const float*)d_in[3];
    float* out = (float*)d_out;

    // Workspace layout (everything fp32, chunked over batches):
    //   pos   C*N fp32                    = 2 MiB   (persistent)
    //   qkv   chunkB * 3C*N fp32          = chunkB * 6 MiB
    //   P     chunkB * N*N  fp32          = chunkB * 4 MiB
    const size_t pos_bytes   = (size_t)C_ * N_ * sizeof(float);
    const size_t qkvb_bytes  = (size_t)M3C * N_ * sizeof(float);   // per batch
    const size_t pb_bytes    = (size_t)N_ * N_ * sizeof(float);    // per batch
    const size_t per_batch   = qkvb_bytes + pb_bytes;              // 10 MiB

    size_t rem = (ws_size > pos_bytes) ? (ws_size - pos_bytes) : 0;
    int chunkB = (int)(rem / per_batch);
    if (chunkB < 1)  chunkB = 1;
    if (chunkB > B_) chunkB = B_;

    char* ws = (char*)d_ws;
    float* pos = (float*)ws;
    float* qkv = (float*)(ws + pos_bytes);
    float* P   = (float*)(ws + pos_bytes + (size_t)chunkB * qkvb_bytes);

    dim3 blk(16, 16);
    pos_kernel<<<(C_ * N_ + 255) / 256, 256, 0, stream>>>(rel_h, rel_w, pos);

    for (int b0 = 0; b0 < B_; b0 += chunkB) {
        int nb = (b0 + chunkB <= B_) ? chunkB : (B_ - b0);
        const float* x_b   = x   + (size_t)b0 * C_ * N_;
        float*       out_b = out + (size_t)b0 * C_ * N_;
        qkv_gemm<<<dim3(N_ / 64, M3C / 64, nb), blk, 0, stream>>>(Wm, x_b, qkv);
        s_gemm  <<<dim3(N_ / 64, N_ / 64, nb), blk, 0, stream>>>(qkv, pos, P);
        softmax_kernel<<<nb * N_, 256, 0, stream>>>(P);
        out_gemm<<<dim3(N_ / 64, C_ / 64, nb), blk, 0, stream>>>(qkv, P, out_b);
    }
}